// Round 14
// baseline (280.718 us; speedup 1.0000x reference)
//
#include <hip/hip_runtime.h>
#include <hip/hip_bf16.h>

#define TSEQ 2048
#define DH   64
#define NBH  32      // B*H
#define KT   32      // k rows per tile per stream
#define NIT  32      // (TSEQ/2)/KT iterations per stream

typedef __attribute__((ext_vector_type(8)))  short short8_t;
typedef __attribute__((ext_vector_type(16))) float f32x16;
typedef __attribute__((ext_vector_type(4)))  unsigned short ushort4_t;

#define LOG2E 1.44269504088896340736f
#define MSUB  12.0f   // static softmax max (log2 domain); |scores*log2e| bounded ~9

__device__ __forceinline__ unsigned short f2bf(float f) {
    unsigned int u = __float_as_uint(f);
    return (unsigned short)((u + 0x7fffu + ((u >> 16) & 1u)) >> 16);
}

__device__ __forceinline__ unsigned int cvtpk(float lo, float hi) {
    unsigned int r;
    asm("v_cvt_pk_bf16_f32 %0, %1, %2" : "=v"(r) : "v"(lo), "v"(hi));
    return r;
}

// fast exp2: compiler intrinsic (backend handles TRANS hazards) or libm fallback.
// NEVER raw inline-asm v_exp_f32 (R9 lesson: TRANS hazard invisible to compiler).
__device__ __forceinline__ float exp2r(float x) {
#if __has_builtin(__builtin_amdgcn_exp2f)
    return __builtin_amdgcn_exp2f(x);
#else
    return exp2f(x);
#endif
}

#define GL2L16(g, l) __builtin_amdgcn_global_load_lds( \
    (__attribute__((address_space(1))) void*)(void*)(g), \
    (__attribute__((address_space(3))) void*)(l), 16, 0, 0)

// 128B-row K tiles: slot = row&7  (R4-R13-verified)
__device__ __forceinline__ unsigned int kswz(unsigned int row, unsigned int cb) {
    return row * 128u + (cb ^ ((row & 7u) << 4));
}
// 64B-row V tiles: slot ((row>>1)&3)  (R4-R13-verified)
__device__ __forceinline__ unsigned int vswz(unsigned int row, unsigned int cb) {
    return row * 64u + (cb ^ (((row >> 1) & 3u) << 4));
}

// fused prep: blocks [0,2048) convert K fp32->bf16; blocks [2048,3072) transpose V
__global__ __launch_bounds__(256) void prep_kernel(const float* __restrict__ K,
                                                   unsigned short* __restrict__ Kb,
                                                   const float* __restrict__ V,
                                                   unsigned short* __restrict__ Vt) {
    __shared__ float tile[64][65];
    const int tid = threadIdx.x;
    if (blockIdx.x < 2048) {
        int i = blockIdx.x * 256 + tid;
        const float4* s = reinterpret_cast<const float4*>(K) + (size_t)i * 2;
        float4 a = s[0], b = s[1];
        short8_t o;
        o[0] = (short)f2bf(a.x); o[1] = (short)f2bf(a.y);
        o[2] = (short)f2bf(a.z); o[3] = (short)f2bf(a.w);
        o[4] = (short)f2bf(b.x); o[5] = (short)f2bf(b.y);
        o[6] = (short)f2bf(b.z); o[7] = (short)f2bf(b.w);
        *reinterpret_cast<short8_t*>(Kb + (size_t)i * 8) = o;
        return;
    }
    const int vbid = blockIdx.x - 2048;
    const int bh = vbid >> 5;
    const int t0 = (vbid & 31) * 64;
    const float* src = V + ((size_t)bh * TSEQ + t0) * DH;
#pragma unroll
    for (int it = 0; it < 4; ++it) {
        int idx = tid + it * 256;
        int row = idx >> 4;
        int c   = (idx & 15) * 4;
        float4 v = *reinterpret_cast<const float4*>(src + row * DH + c);
        tile[row][c + 0] = v.x; tile[row][c + 1] = v.y;
        tile[row][c + 2] = v.z; tile[row][c + 3] = v.w;
    }
    __syncthreads();
#pragma unroll
    for (int it = 0; it < 4; ++it) {
        int idx = tid + it * 256;
        int d  = idx >> 4;
        int c  = (idx & 15) * 4;
        ushort4_t o;
        o[0] = f2bf(tile[c + 0][d]); o[1] = f2bf(tile[c + 1][d]);
        o[2] = f2bf(tile[c + 2][d]); o[3] = f2bf(tile[c + 3][d]);
        *reinterpret_cast<ushort4_t*>(Vt + ((size_t)bh * DH + d) * TSEQ + t0 + c) = o;
    }
}

// Flash attention, cross-tile pipelined: 256 threads = 2 k-streams x 2 q-waves,
// grid 1024 (4 blocks/CU, 16 waves/CU). Each barrier round computes QK+softmax
// of tile t AND PV of tile t-1 (packed P + V frags carried in registers) so the
// scheduler interleaves two independent chains. Counted-vmcnt + raw s_barrier
// 2-deep staging (R13-verified schedule, unchanged). Static-max softmax.
__global__ __launch_bounds__(256, 4) void attn_kernel(const float* __restrict__ Qf,
                                                      const unsigned short* __restrict__ Kb,
                                                      const unsigned short* __restrict__ Vt,
                                                      const float* __restrict__ mask,
                                                      float* __restrict__ out) {
    // [0,32K): 2 bufs x {K s0|K s1|V s0|V s1} 4KB each; [32K,40K): mask f32
    __shared__ char lds[40960];
    float* smsk = reinterpret_cast<float*>(lds + 32768);

    const int tid  = threadIdx.x;
    const int wave = tid >> 6;
    const int lane = tid & 63;
    const int l31  = lane & 31;
    const int hi   = lane >> 5;
    const int s    = wave >> 1;    // k-stream
    const int qw   = wave & 1;     // q-wave (32 rows)

    // bijective XCD swizzle: 1024 blocks (%8==0), 4 bh per XCD
    const int bid   = blockIdx.x;
    const int chunk = bid >> 3;
    const int bh    = (bid & 7) * 4 + (chunk >> 5);
    const int qb    = chunk & 31;
    const int q0    = qb * 64 + qw * 32;
    const int b     = bh >> 4;

    // staging: wave w writes segs {w, w+4, w+8, w+12} (1KB each) per buffer
    const char* gKc = reinterpret_cast<const char*>(Kb + (size_t)bh * TSEQ * DH);
    const char* gVc = reinterpret_cast<const char*>(Vt + (size_t)bh * DH * TSEQ);
    const unsigned int kr  = wave * 8 + (lane >> 3);
    const unsigned int kcb = (lane & 7) * 16;
    const unsigned int vd  = wave * 16 + (lane >> 2);
    const unsigned int vcb = (lane & 3) * 16;
    const char* p0 = gKc + (size_t)kr * 128 + (kcb ^ ((kr & 7u) << 4));          // K s0
    const char* p1 = p0 + (size_t)1024 * 128;                                    // K s1
    const char* p2 = gVc + (size_t)vd * 4096 + (vcb ^ (((vd >> 1) & 3u) << 4));  // V s0
    const char* p3 = p2 + (size_t)1024 * 2;                                      // V s1
    const unsigned int lo0 = (wave +  0) * 1024 + lane * 16;
    const unsigned int lo1 = (wave +  4) * 1024 + lane * 16;
    const unsigned int lo2 = (wave +  8) * 1024 + lane * 16;
    const unsigned int lo3 = (wave + 12) * 1024 + lane * 16;

    auto stage = [&](int buf) {
        char* base = lds + buf * 16384;
        GL2L16(p0, base + lo0);
        GL2L16(p1, base + lo1);
        GL2L16(p2, base + lo2);
        GL2L16(p3, base + lo3);
        p0 += KT * 128; p1 += KT * 128; p2 += KT * 2; p3 += KT * 2;
    };

    // prologue: start tiles 0 and 1 immediately
    stage(0);
    stage(1);

    // stage mask row: *log2e - MSUB
    {
        const float4* m4 = reinterpret_cast<const float4*>(mask + (size_t)b * TSEQ);
        float4* s4 = reinterpret_cast<float4*>(smsk);
#pragma unroll
        for (int i = 0; i < 2; ++i) {
            int idx = tid + i * 256;
            float4 v = m4[idx];
            float4 w;
            w.x = v.x * LOG2E - MSUB; w.y = v.y * LOG2E - MSUB;
            w.z = v.z * LOG2E - MSUB; w.w = v.w * LOG2E - MSUB;
            s4[idx] = w;
        }
    }

    // Q B-frags from fp32 global, scale*log2e folded [R5-R13-verified]
    const float QS = 0.125f * LOG2E;
    const float* qrow = Qf + ((size_t)bh * TSEQ + q0 + l31) * DH;
    short8_t qf[4];
#pragma unroll
    for (int dc = 0; dc < 4; ++dc) {
        float4 v0 = *reinterpret_cast<const float4*>(qrow + 16 * dc + 8 * hi);
        float4 v1 = *reinterpret_cast<const float4*>(qrow + 16 * dc + 8 * hi + 4);
        union { unsigned int u[4]; short8_t s8; } pk;
        pk.u[0] = cvtpk(v0.x * QS, v0.y * QS);
        pk.u[1] = cvtpk(v0.z * QS, v0.w * QS);
        pk.u[2] = cvtpk(v1.x * QS, v1.y * QS);
        pk.u[3] = cvtpk(v1.z * QS, v1.w * QS);
        qf[dc] = pk.s8;
    }

    f32x16 oacc0, oacc1;
#pragma unroll
    for (int r = 0; r < 16; ++r) { oacc0[r] = 0.f; oacc1[r] = 0.f; }
    float lsum = 0.f;

    const char* const cKbase = lds + s * 4096;
    const char* const cVbase = lds + 8192 + s * 4096;
    const int kofs = s * 1024;

    // QK + softmax of tile it; emits packed-P words (pf[8]) and V frags (vf[4])
    auto qksm_tile = [&](int cur, int it, unsigned int* pf, short8_t* vf) {
        const char* cK = cKbase + cur * 16384;
        const char* cV = cVbase + cur * 16384;

        short8_t kf0 = *reinterpret_cast<const short8_t*>(cK + kswz(l31, 16 * hi));
        short8_t kf1 = *reinterpret_cast<const short8_t*>(cK + kswz(l31, 32 + 16 * hi));
        short8_t kf2 = *reinterpret_cast<const short8_t*>(cK + kswz(l31, 64 + 16 * hi));
        short8_t kf3 = *reinterpret_cast<const short8_t*>(cK + kswz(l31, 96 + 16 * hi));

        const float* mb = &smsk[kofs + it * KT + 4 * hi];
        float4 mv0 = *reinterpret_cast<const float4*>(mb);
        float4 mv1 = *reinterpret_cast<const float4*>(mb + 8);
        float4 mv2 = *reinterpret_cast<const float4*>(mb + 16);
        float4 mv3 = *reinterpret_cast<const float4*>(mb + 24);
        f32x16 sc;
        sc[0]  = mv0.x; sc[1]  = mv0.y; sc[2]  = mv0.z; sc[3]  = mv0.w;
        sc[4]  = mv1.x; sc[5]  = mv1.y; sc[6]  = mv1.z; sc[7]  = mv1.w;
        sc[8]  = mv2.x; sc[9]  = mv2.y; sc[10] = mv2.z; sc[11] = mv2.w;
        sc[12] = mv3.x; sc[13] = mv3.y; sc[14] = mv3.z; sc[15] = mv3.w;

        __builtin_amdgcn_s_setprio(1);
        sc = __builtin_amdgcn_mfma_f32_32x32x16_bf16(kf0, qf[0], sc, 0, 0, 0);
        sc = __builtin_amdgcn_mfma_f32_32x32x16_bf16(kf1, qf[1], sc, 0, 0, 0);
        sc = __builtin_amdgcn_mfma_f32_32x32x16_bf16(kf2, qf[2], sc, 0, 0, 0);
        sc = __builtin_amdgcn_mfma_f32_32x32x16_bf16(kf3, qf[3], sc, 0, 0, 0);
        __builtin_amdgcn_s_setprio(0);

        // softmax + pack (static max; pf order {a0,a2,a1,a3} per c, R13-verified)
#pragma unroll
        for (int c = 0; c < 2; ++c) {
            float e0 = exp2r(sc[8*c+0]), e1 = exp2r(sc[8*c+1]);
            float e2 = exp2r(sc[8*c+2]), e3 = exp2r(sc[8*c+3]);
            float e4 = exp2r(sc[8*c+4]), e5 = exp2r(sc[8*c+5]);
            float e6 = exp2r(sc[8*c+6]), e7 = exp2r(sc[8*c+7]);
            lsum += ((e0+e1)+(e2+e3)) + ((e4+e5)+(e6+e7));
            unsigned int a0 = cvtpk(e0, e1), a2 = cvtpk(e2, e3);
            unsigned int a1 = cvtpk(e4, e5), a3 = cvtpk(e6, e7);
            asm("v_permlane32_swap_b32 %0, %1" : "+v"(a0), "+v"(a1));
            asm("v_permlane32_swap_b32 %0, %1" : "+v"(a2), "+v"(a3));
            pf[4*c+0] = a0; pf[4*c+1] = a2; pf[4*c+2] = a1; pf[4*c+3] = a3;
        }
        // V frags last (sc is dead by now -> lower peak liveness)
        vf[0] = *reinterpret_cast<const short8_t*>(cV + vswz(l31,      16 * hi));
        vf[1] = *reinterpret_cast<const short8_t*>(cV + vswz(32 + l31, 16 * hi));
        vf[2] = *reinterpret_cast<const short8_t*>(cV + vswz(l31,      32 + 16 * hi));
        vf[3] = *reinterpret_cast<const short8_t*>(cV + vswz(32 + l31, 32 + 16 * hi));
    };

    // PV of a carried tile: registers only (legal anywhere in the round)
    auto pv_tile = [&](const unsigned int* pf, const short8_t* vf) {
#pragma unroll
        for (int c = 0; c < 2; ++c) {
            union { unsigned int u[4]; short8_t s8; } pu;
            pu.u[0] = pf[4*c+0]; pu.u[1] = pf[4*c+1];
            pu.u[2] = pf[4*c+2]; pu.u[3] = pf[4*c+3];
            __builtin_amdgcn_s_setprio(1);
            oacc0 = __builtin_amdgcn_mfma_f32_32x32x16_bf16(vf[2*c+0], pu.s8, oacc0, 0, 0, 0);
            oacc1 = __builtin_amdgcn_mfma_f32_32x32x16_bf16(vf[2*c+1], pu.s8, oacc1, 0, 0, 0);
            __builtin_amdgcn_s_setprio(0);
        }
    };

    __syncthreads();   // mask + tiles 0,1 visible (full fence, one-time)

    unsigned int pfP[8]; short8_t vP[4];
    // round 0: QK+SM(0) only (nothing to PV yet)
    qksm_tile(0, 0, pfP, vP);
    __builtin_amdgcn_sched_barrier(0);
    __builtin_amdgcn_s_barrier();                 // all waves done reading tile 0
    __builtin_amdgcn_sched_barrier(0);
    stage(0);                                     // tile 2 -> buf0

    // rounds 1..NIT-2: QK+SM(t) || PV(t-1); carried in registers
#pragma unroll 2
    for (int t = 1; t < NIT - 1; ++t) {
        asm volatile("s_waitcnt vmcnt(4)" ::: "memory");
        __builtin_amdgcn_s_barrier();
        __builtin_amdgcn_sched_barrier(0);
        unsigned int pfC[8]; short8_t vC[4];
        qksm_tile(t & 1, t, pfC, vC);
        pv_tile(pfP, vP);
        __builtin_amdgcn_sched_barrier(0);
        __builtin_amdgcn_s_barrier();
        __builtin_amdgcn_sched_barrier(0);
        if (t <= NIT - 3) stage(t & 1);
#pragma unroll
        for (int i = 0; i < 8; ++i) pfP[i] = pfC[i];
#pragma unroll
        for (int i = 0; i < 4; ++i) vP[i] = vC[i];
    }
    // last round peeled: vmcnt(0) (only tile NIT-1's loads outstanding)
    asm volatile("s_waitcnt vmcnt(0)" ::: "memory");
    __builtin_amdgcn_s_barrier();
    __builtin_amdgcn_sched_barrier(0);
    {
        unsigned int pfC[8]; short8_t vC[4];
        qksm_tile((NIT - 1) & 1, NIT - 1, pfC, vC);
        pv_tile(pfP, vP);
        pv_tile(pfC, vC);
    }

    __syncthreads();   // LDS reusable for merge

    // split-K merge: static max -> partials just add. Stream-1 waves write O^T,l.
    float lt = lsum + __shfl_xor(lsum, 32);
    if (s == 1) {
        char* wp = lds + qw * 8192;
#pragma unroll
        for (int i = 0; i < 8; ++i) {
            float4 v;
            if (i < 4) { v.x = oacc0[4*i]; v.y = oacc0[4*i+1]; v.z = oacc0[4*i+2]; v.w = oacc0[4*i+3]; }
            else       { v.x = oacc1[4*(i-4)]; v.y = oacc1[4*(i-4)+1]; v.z = oacc1[4*(i-4)+2]; v.w = oacc1[4*(i-4)+3]; }
            *reinterpret_cast<float4*>(wp + lane * 128 + ((i * 16) ^ ((lane & 7u) << 4))) = v;
        }
        if (hi == 0) reinterpret_cast<float*>(lds + 32768 + qw * 256)[l31] = lt;
    }
    __syncthreads();
    if (s == 0) {
        const char* rp = lds + qw * 8192;
        float ltt = lt + reinterpret_cast<const float*>(lds + 32768 + qw * 256)[l31];
        float inv = 1.0f / ltt;
        float* orow = out + ((size_t)bh * TSEQ + q0 + l31) * DH;
#pragma unroll
        for (int i = 0; i < 8; ++i) {
            float4 o = *reinterpret_cast<const float4*>(rp + lane * 128 + ((i * 16) ^ ((lane & 7u) << 4)));
            float4 v;
            if (i < 4) {
                v.x = (oacc0[4*i]   + o.x) * inv; v.y = (oacc0[4*i+1] + o.y) * inv;
                v.z = (oacc0[4*i+2] + o.z) * inv; v.w = (oacc0[4*i+3] + o.w) * inv;
            } else {
                v.x = (oacc1[4*(i-4)]   + o.x) * inv; v.y = (oacc1[4*(i-4)+1] + o.y) * inv;
                v.z = (oacc1[4*(i-4)+2] + o.z) * inv; v.w = (oacc1[4*(i-4)+3] + o.w) * inv;
            }
            const int db = i >> 2, rr = i & 3;
            *reinterpret_cast<float4*>(orow + 32 * db + 8 * rr + 4 * hi) = v;
        }
    }
}

extern "C" void kernel_launch(void* const* d_in, const int* in_sizes, int n_in,
                              void* d_out, int out_size, void* d_ws, size_t ws_size,
                              hipStream_t stream) {
    const float* Q    = (const float*)d_in[0];
    const float* K    = (const float*)d_in[1];
    const float* V    = (const float*)d_in[2];
    const float* mask = (const float*)d_in[3];
    float* out = (float*)d_out;

    const size_t N = (size_t)NBH * TSEQ * DH;
    unsigned short* Kb = (unsigned short*)d_ws;   // 8 MB
    unsigned short* Vt = Kb + N;                  // 8 MB

    hipLaunchKernelGGL(prep_kernel, dim3(2048 + 1024), dim3(256), 0, stream, K, Kb, V, Vt);
    hipLaunchKernelGGL(attn_kernel, dim3(32 * NBH), dim3(256), 0, stream,
                       Q, Kb, Vt, mask, out);
}

// Round 17
// 57.204 us; speedup vs baseline: 4.9073x; 4.9073x over previous
//
#include <hip/hip_runtime.h>
#include <hip/hip_bf16.h>

#define TSEQ 2048
#define DH   64
#define NBH  32      // B*H
#define KT   32      // k rows per tile per stream
#define NIT  32      // (TSEQ/2)/KT iterations per stream

typedef __attribute__((ext_vector_type(8)))  short short8_t;
typedef __attribute__((ext_vector_type(16))) float f32x16;
typedef __attribute__((ext_vector_type(4)))  unsigned short ushort4_t;

#define LOG2E 1.44269504088896340736f
#define MSUB  12.0f   // static softmax max (log2 domain); |scores*log2e| bounded ~9

__device__ __forceinline__ unsigned short f2bf(float f) {
    unsigned int u = __float_as_uint(f);
    return (unsigned short)((u + 0x7fffu + ((u >> 16) & 1u)) >> 16);
}

__device__ __forceinline__ unsigned int cvtpk(float lo, float hi) {
    unsigned int r;
    asm("v_cvt_pk_bf16_f32 %0, %1, %2" : "=v"(r) : "v"(lo), "v"(hi));
    return r;
}

// fast exp2: compiler intrinsic (backend handles TRANS hazards) or libm fallback.
// NEVER raw inline-asm v_exp_f32 (R9 lesson: TRANS hazard invisible to compiler).
__device__ __forceinline__ float exp2r(float x) {
#if __has_builtin(__builtin_amdgcn_exp2f)
    return __builtin_amdgcn_exp2f(x);
#else
    return exp2f(x);
#endif
}

#define GL2L16(g, l) __builtin_amdgcn_global_load_lds( \
    (__attribute__((address_space(1))) void*)(void*)(g), \
    (__attribute__((address_space(3))) void*)(l), 16, 0, 0)

// 128B-row K tiles: slot = row&7  (R4-R13-verified)
__device__ __forceinline__ unsigned int kswz(unsigned int row, unsigned int cb) {
    return row * 128u + (cb ^ ((row & 7u) << 4));
}
// 64B-row V tiles: slot ((row>>1)&3)  (R4-R13-verified)
__device__ __forceinline__ unsigned int vswz(unsigned int row, unsigned int cb) {
    return row * 64u + (cb ^ (((row >> 1) & 3u) << 4));
}

// fused prep: blocks [0,2048) convert K fp32->bf16; blocks [2048,3072) transpose V
__global__ __launch_bounds__(256) void prep_kernel(const float* __restrict__ K,
                                                   unsigned short* __restrict__ Kb,
                                                   const float* __restrict__ V,
                                                   unsigned short* __restrict__ Vt) {
    __shared__ float tile[64][65];
    const int tid = threadIdx.x;
    if (blockIdx.x < 2048) {
        int i = blockIdx.x * 256 + tid;
        const float4* s = reinterpret_cast<const float4*>(K) + (size_t)i * 2;
        float4 a = s[0], b = s[1];
        short8_t o;
        o[0] = (short)f2bf(a.x); o[1] = (short)f2bf(a.y);
        o[2] = (short)f2bf(a.z); o[3] = (short)f2bf(a.w);
        o[4] = (short)f2bf(b.x); o[5] = (short)f2bf(b.y);
        o[6] = (short)f2bf(b.z); o[7] = (short)f2bf(b.w);
        *reinterpret_cast<short8_t*>(Kb + (size_t)i * 8) = o;
        return;
    }
    const int vbid = blockIdx.x - 2048;
    const int bh = vbid >> 5;
    const int t0 = (vbid & 31) * 64;
    const float* src = V + ((size_t)bh * TSEQ + t0) * DH;
#pragma unroll
    for (int it = 0; it < 4; ++it) {
        int idx = tid + it * 256;
        int row = idx >> 4;
        int c   = (idx & 15) * 4;
        float4 v = *reinterpret_cast<const float4*>(src + row * DH + c);
        tile[row][c + 0] = v.x; tile[row][c + 1] = v.y;
        tile[row][c + 2] = v.z; tile[row][c + 3] = v.w;
    }
    __syncthreads();
#pragma unroll
    for (int it = 0; it < 4; ++it) {
        int idx = tid + it * 256;
        int d  = idx >> 4;
        int c  = (idx & 15) * 4;
        ushort4_t o;
        o[0] = f2bf(tile[c + 0][d]); o[1] = f2bf(tile[c + 1][d]);
        o[2] = f2bf(tile[c + 2][d]); o[3] = f2bf(tile[c + 3][d]);
        *reinterpret_cast<ushort4_t*>(Vt + ((size_t)bh * DH + d) * TSEQ + t0 + c) = o;
    }
}

// Flash attention: R10 body (2 k-streams x 2 q-waves, 64 q/wave via 2 q-sets,
// raw exp2 fused softmax) + TRIPLE-buffered ONE-barrier-per-round skeleton.
// Round t: vmcnt(4) -> s_barrier -> do_tile(t, bufA) -> stage(t+2 -> bufC).
// bufC holds tile t-1, consumed before this round's barrier by all waves ->
// single barrier separates last read from overwrite. do_tile/staging/merge
// byte-identical to R10 (passed, 51.4us).
__global__ __launch_bounds__(256, 2) void attn_kernel(const float* __restrict__ Qf,
                                                      const unsigned short* __restrict__ Kb,
                                                      const unsigned short* __restrict__ Vt,
                                                      const float* __restrict__ mask,
                                                      float* __restrict__ out) {
    // bufs at 0 / 16K / 32K (each {K s0|K s1|V s0|V s1} 4KB); mask f32 at 48K
    __shared__ char lds[57344];
    float* smsk = reinterpret_cast<float*>(lds + 49152);

    const int tid  = threadIdx.x;
    const int wave = tid >> 6;
    const int lane = tid & 63;
    const int l31  = lane & 31;
    const int hi   = lane >> 5;
    const int s    = wave >> 1;    // k-stream
    const int qw   = wave & 1;     // q-wave (64 rows)

    // bijective XCD swizzle (512 blocks % 8 == 0): 4 bh per XCD
    const int bid = blockIdx.x;
    const int bh  = (bid & 7) * 4 + (bid >> 7);
    const int qb  = (bid >> 3) & 15;
    const int q0  = qb * 128 + qw * 64;
    const int b   = bh >> 4;

    // staging: wave w writes segs {w, w+4, w+8, w+12} (1KB each) per buffer
    const char* gKc = reinterpret_cast<const char*>(Kb + (size_t)bh * TSEQ * DH);
    const char* gVc = reinterpret_cast<const char*>(Vt + (size_t)bh * DH * TSEQ);
    const unsigned int kr  = wave * 8 + (lane >> 3);
    const unsigned int kcb = (lane & 7) * 16;
    const unsigned int vd  = wave * 16 + (lane >> 2);
    const unsigned int vcb = (lane & 3) * 16;
    const char* p0 = gKc + (size_t)kr * 128 + (kcb ^ ((kr & 7u) << 4));          // K s0
    const char* p1 = p0 + (size_t)1024 * 128;                                    // K s1
    const char* p2 = gVc + (size_t)vd * 4096 + (vcb ^ (((vd >> 1) & 3u) << 4));  // V s0
    const char* p3 = p2 + (size_t)1024 * 2;                                      // V s1
    const unsigned int lo0 = (wave +  0) * 1024 + lane * 16;
    const unsigned int lo1 = (wave +  4) * 1024 + lane * 16;
    const unsigned int lo2 = (wave +  8) * 1024 + lane * 16;
    const unsigned int lo3 = (wave + 12) * 1024 + lane * 16;

    auto stage = [&](char* base) {
        GL2L16(p0, base + lo0);
        GL2L16(p1, base + lo1);
        GL2L16(p2, base + lo2);
        GL2L16(p3, base + lo3);
        p0 += KT * 128; p1 += KT * 128; p2 += KT * 2; p3 += KT * 2;
    };

    // prologue: tiles 0 -> buf0, 1 -> buf1 (drained by the one-time syncthreads)
    stage(lds);
    stage(lds + 16384);

    // stage mask row: *log2e - MSUB
    {
        const float4* m4 = reinterpret_cast<const float4*>(mask + (size_t)b * TSEQ);
        float4* s4 = reinterpret_cast<float4*>(smsk);
#pragma unroll
        for (int i = 0; i < 2; ++i) {
            int idx = tid + i * 256;
            float4 v = m4[idx];
            float4 w;
            w.x = v.x * LOG2E - MSUB; w.y = v.y * LOG2E - MSUB;
            w.z = v.z * LOG2E - MSUB; w.w = v.w * LOG2E - MSUB;
            s4[idx] = w;
        }
    }

    // Q B-frags (2 q-sets) from fp32 global, scale*log2e folded [R7-R10-verified]
    const float QS = 0.125f * LOG2E;
    short8_t qfA[4], qfB[4];
#pragma unroll
    for (int qs = 0; qs < 2; ++qs) {
        const float* qrow = Qf + ((size_t)bh * TSEQ + q0 + qs * 32 + l31) * DH;
#pragma unroll
        for (int dc = 0; dc < 4; ++dc) {
            float4 v0 = *reinterpret_cast<const float4*>(qrow + 16 * dc + 8 * hi);
            float4 v1 = *reinterpret_cast<const float4*>(qrow + 16 * dc + 8 * hi + 4);
            union { unsigned int u[4]; short8_t s8; } pk;
            pk.u[0] = cvtpk(v0.x * QS, v0.y * QS);
            pk.u[1] = cvtpk(v0.z * QS, v0.w * QS);
            pk.u[2] = cvtpk(v1.x * QS, v1.y * QS);
            pk.u[3] = cvtpk(v1.z * QS, v1.w * QS);
            if (qs == 0) qfA[dc] = pk.s8; else qfB[dc] = pk.s8;
        }
    }

    f32x16 oA0, oA1, oB0, oB1;
#pragma unroll
    for (int r = 0; r < 16; ++r) { oA0[r] = 0.f; oA1[r] = 0.f; oB0[r] = 0.f; oB1[r] = 0.f; }
    float lA = 0.f, lB = 0.f;

    const int kofs = s * 1024;

    // R10's do_tile, parameterized by buffer base (K at +s*4K, V at +8K+s*4K)
    auto do_tile = [&](const char* bb, int it) {
        const char* cK = bb + s * 4096;
        const char* cV = bb + 8192 + s * 4096;

        // K A-frags (shared by both q-sets)
        short8_t kf0 = *reinterpret_cast<const short8_t*>(cK + kswz(l31, 16 * hi));
        short8_t kf1 = *reinterpret_cast<const short8_t*>(cK + kswz(l31, 32 + 16 * hi));
        short8_t kf2 = *reinterpret_cast<const short8_t*>(cK + kswz(l31, 64 + 16 * hi));
        short8_t kf3 = *reinterpret_cast<const short8_t*>(cK + kswz(l31, 96 + 16 * hi));

        // C-init with (mask*log2e - MSUB), reused by both q-sets
        const float* mb = &smsk[kofs + it * KT + 4 * hi];
        float4 mv0 = *reinterpret_cast<const float4*>(mb);
        float4 mv1 = *reinterpret_cast<const float4*>(mb + 8);
        float4 mv2 = *reinterpret_cast<const float4*>(mb + 16);
        float4 mv3 = *reinterpret_cast<const float4*>(mb + 24);
        f32x16 scA;
        scA[0]  = mv0.x; scA[1]  = mv0.y; scA[2]  = mv0.z; scA[3]  = mv0.w;
        scA[4]  = mv1.x; scA[5]  = mv1.y; scA[6]  = mv1.z; scA[7]  = mv1.w;
        scA[8]  = mv2.x; scA[9]  = mv2.y; scA[10] = mv2.z; scA[11] = mv2.w;
        scA[12] = mv3.x; scA[13] = mv3.y; scA[14] = mv3.z; scA[15] = mv3.w;
        f32x16 scB = scA;

        // S^T = K . Q^T for both q-sets (K frags reused)
        __builtin_amdgcn_s_setprio(1);
        scA = __builtin_amdgcn_mfma_f32_32x32x16_bf16(kf0, qfA[0], scA, 0, 0, 0);
        scB = __builtin_amdgcn_mfma_f32_32x32x16_bf16(kf0, qfB[0], scB, 0, 0, 0);
        scA = __builtin_amdgcn_mfma_f32_32x32x16_bf16(kf1, qfA[1], scA, 0, 0, 0);
        scB = __builtin_amdgcn_mfma_f32_32x32x16_bf16(kf1, qfB[1], scB, 0, 0, 0);
        scA = __builtin_amdgcn_mfma_f32_32x32x16_bf16(kf2, qfA[2], scA, 0, 0, 0);
        scB = __builtin_amdgcn_mfma_f32_32x32x16_bf16(kf2, qfB[2], scB, 0, 0, 0);
        scA = __builtin_amdgcn_mfma_f32_32x32x16_bf16(kf3, qfA[3], scA, 0, 0, 0);
        scB = __builtin_amdgcn_mfma_f32_32x32x16_bf16(kf3, qfB[3], scB, 0, 0, 0);
        __builtin_amdgcn_s_setprio(0);

        // V A-frags (shared by both q-sets)
        short8_t vf00 = *reinterpret_cast<const short8_t*>(cV + vswz(l31,      16 * hi));
        short8_t vf01 = *reinterpret_cast<const short8_t*>(cV + vswz(32 + l31, 16 * hi));
        short8_t vf10 = *reinterpret_cast<const short8_t*>(cV + vswz(l31,      32 + 16 * hi));
        short8_t vf11 = *reinterpret_cast<const short8_t*>(cV + vswz(32 + l31, 32 + 16 * hi));

        // fused softmax (raw exp2 + l-add + cvtpk), 2 halves interleaved with PV
#pragma unroll
        for (int c = 0; c < 2; ++c) {
            unsigned int a0, a1, a2, a3, b0, b1, b2, b3;
            {
                float e0 = exp2r(scA[8*c+0]), e1 = exp2r(scA[8*c+1]);
                float e2 = exp2r(scA[8*c+2]), e3 = exp2r(scA[8*c+3]);
                float e4 = exp2r(scA[8*c+4]), e5 = exp2r(scA[8*c+5]);
                float e6 = exp2r(scA[8*c+6]), e7 = exp2r(scA[8*c+7]);
                lA += ((e0+e1)+(e2+e3)) + ((e4+e5)+(e6+e7));
                a0 = cvtpk(e0, e1); a2 = cvtpk(e2, e3);
                a1 = cvtpk(e4, e5); a3 = cvtpk(e6, e7);
            }
            {
                float e0 = exp2r(scB[8*c+0]), e1 = exp2r(scB[8*c+1]);
                float e2 = exp2r(scB[8*c+2]), e3 = exp2r(scB[8*c+3]);
                float e4 = exp2r(scB[8*c+4]), e5 = exp2r(scB[8*c+5]);
                float e6 = exp2r(scB[8*c+6]), e7 = exp2r(scB[8*c+7]);
                lB += ((e0+e1)+(e2+e3)) + ((e4+e5)+(e6+e7));
                b0 = cvtpk(e0, e1); b2 = cvtpk(e2, e3);
                b1 = cvtpk(e4, e5); b3 = cvtpk(e6, e7);
            }
            asm("v_permlane32_swap_b32 %0, %1" : "+v"(a0), "+v"(a1));
            asm("v_permlane32_swap_b32 %0, %1" : "+v"(a2), "+v"(a3));
            asm("v_permlane32_swap_b32 %0, %1" : "+v"(b0), "+v"(b1));
            asm("v_permlane32_swap_b32 %0, %1" : "+v"(b2), "+v"(b3));
            union { unsigned int u[4]; short8_t s8; } pfA, pfB;
            pfA.u[0] = a0; pfA.u[1] = a2; pfA.u[2] = a1; pfA.u[3] = a3;
            pfB.u[0] = b0; pfB.u[1] = b2; pfB.u[2] = b1; pfB.u[3] = b3;
            short8_t vf0 = c ? vf10 : vf00;
            short8_t vf1 = c ? vf11 : vf01;
            __builtin_amdgcn_s_setprio(1);
            oA0 = __builtin_amdgcn_mfma_f32_32x32x16_bf16(vf0, pfA.s8, oA0, 0, 0, 0);
            oB0 = __builtin_amdgcn_mfma_f32_32x32x16_bf16(vf0, pfB.s8, oB0, 0, 0, 0);
            oA1 = __builtin_amdgcn_mfma_f32_32x32x16_bf16(vf1, pfA.s8, oA1, 0, 0, 0);
            oB1 = __builtin_amdgcn_mfma_f32_32x32x16_bf16(vf1, pfB.s8, oB1, 0, 0, 0);
            __builtin_amdgcn_s_setprio(0);
        }
    };

    __syncthreads();   // mask + tiles 0,1 visible (full drain, one-time)

    // one-barrier rounds with 3-buffer rotation:
    //   bufA = tile t, bufB = tile t+1, bufC = tile t-1's buffer (stage dest)
    char* bufA = lds;
    char* bufB = lds + 16384;
    char* bufC = lds + 32768;
    for (int t = 0; t < NIT - 1; ++t) {
        asm volatile("s_waitcnt vmcnt(4)" ::: "memory");   // my tile-t loads landed
        __builtin_amdgcn_s_barrier();                      // all waves' tile-t loads landed;
                                                           // also: all waves done reading tile t-1
        __builtin_amdgcn_sched_barrier(0);                 // pin ds_reads below barrier
        do_tile(bufA, t);
        if (t < NIT - 2) stage(bufC);                      // tile t+2 -> tile t-1's buffer
        char* tmp = bufA; bufA = bufB; bufB = bufC; bufC = tmp;
    }
    asm volatile("s_waitcnt vmcnt(0)" ::: "memory");
    __builtin_amdgcn_s_barrier();
    __builtin_amdgcn_sched_barrier(0);
    do_tile(bufA, NIT - 1);

    __syncthreads();   // LDS reusable for merge

    // split-K merge: static max -> partials just add. Stream-1 waves write O^T,l.
    float lAt = lA + __shfl_xor(lA, 32);
    float lBt = lB + __shfl_xor(lB, 32);
    if (s == 1) {
#pragma unroll
        for (int qs = 0; qs < 2; ++qs) {
            char* wp = lds + qw * 16384 + qs * 8192;
            const f32x16& o0 = qs ? oB0 : oA0;
            const f32x16& o1 = qs ? oB1 : oA1;
#pragma unroll
            for (int i = 0; i < 8; ++i) {
                float4 v;
                if (i < 4) { v.x = o0[4*i]; v.y = o0[4*i+1]; v.z = o0[4*i+2]; v.w = o0[4*i+3]; }
                else       { v.x = o1[4*(i-4)]; v.y = o1[4*(i-4)+1]; v.z = o1[4*(i-4)+2]; v.w = o1[4*(i-4)+3]; }
                *reinterpret_cast<float4*>(wp + lane * 128 + ((i * 16) ^ ((lane & 7u) << 4))) = v;
            }
        }
        if (hi == 0) {
            reinterpret_cast<float*>(lds + 32768 + (qw * 2 + 0) * 128)[l31] = lAt;
            reinterpret_cast<float*>(lds + 32768 + (qw * 2 + 1) * 128)[l31] = lBt;
        }
    }
    __syncthreads();
    if (s == 0) {
#pragma unroll
        for (int qs = 0; qs < 2; ++qs) {
            const char* rp = lds + qw * 16384 + qs * 8192;
            const f32x16& o0 = qs ? oB0 : oA0;
            const f32x16& o1 = qs ? oB1 : oA1;
            float lpart = qs ? lBt : lAt;
            float ltt = lpart + reinterpret_cast<const float*>(lds + 32768 + (qw * 2 + qs) * 128)[l31];
            float inv = 1.0f / ltt;
            float* orow = out + ((size_t)bh * TSEQ + q0 + qs * 32 + l31) * DH;
#pragma unroll
            for (int i = 0; i < 8; ++i) {
                float4 o = *reinterpret_cast<const float4*>(rp + lane * 128 + ((i * 16) ^ ((lane & 7u) << 4)));
                float4 v;
                if (i < 4) {
                    v.x = (o0[4*i]   + o.x) * inv; v.y = (o0[4*i+1] + o.y) * inv;
                    v.z = (o0[4*i+2] + o.z) * inv; v.w = (o0[4*i+3] + o.w) * inv;
                } else {
                    v.x = (o1[4*(i-4)]   + o.x) * inv; v.y = (o1[4*(i-4)+1] + o.y) * inv;
                    v.z = (o1[4*(i-4)+2] + o.z) * inv; v.w = (o1[4*(i-4)+3] + o.w) * inv;
                }
                const int db = i >> 2, rr = i & 3;
                *reinterpret_cast<float4*>(orow + 32 * db + 8 * rr + 4 * hi) = v;
            }
        }
    }
}

extern "C" void kernel_launch(void* const* d_in, const int* in_sizes, int n_in,
                              void* d_out, int out_size, void* d_ws, size_t ws_size,
                              hipStream_t stream) {
    const float* Q    = (const float*)d_in[0];
    const float* K    = (const float*)d_in[1];
    const float* V    = (const float*)d_in[2];
    const float* mask = (const float*)d_in[3];
    float* out = (float*)d_out;

    const size_t N = (size_t)NBH * TSEQ * DH;
    unsigned short* Kb = (unsigned short*)d_ws;   // 8 MB
    unsigned short* Vt = Kb + N;                  // 8 MB

    hipLaunchKernelGGL(prep_kernel, dim3(2048 + 1024), dim3(256), 0, stream, K, Kb, V, Vt);
    hipLaunchKernelGGL(attn_kernel, dim3(16 * NBH), dim3(256), 0, stream,
                       Q, Kb, Vt, mask, out);
}

// Round 18
// 56.671 us; speedup vs baseline: 4.9535x; 1.0094x over previous
//
#include <hip/hip_runtime.h>
#include <hip/hip_bf16.h>

#define TSEQ 2048
#define DH   64
#define NBH  32      // B*H
#define KT   64      // k rows per tile per stream
#define NIT  16      // (TSEQ/2)/KT iterations per stream

typedef __attribute__((ext_vector_type(8)))  short short8_t;
typedef __attribute__((ext_vector_type(16))) float f32x16;
typedef __attribute__((ext_vector_type(4)))  unsigned short ushort4_t;

#define LOG2E 1.44269504088896340736f
#define MSUB  12.0f   // static softmax max (log2 domain); |scores*log2e| bounded ~9

__device__ __forceinline__ unsigned short f2bf(float f) {
    unsigned int u = __float_as_uint(f);
    return (unsigned short)((u + 0x7fffu + ((u >> 16) & 1u)) >> 16);
}

__device__ __forceinline__ unsigned int cvtpk(float lo, float hi) {
    unsigned int r;
    asm("v_cvt_pk_bf16_f32 %0, %1, %2" : "=v"(r) : "v"(lo), "v"(hi));
    return r;
}

// fast exp2: compiler intrinsic (backend handles TRANS hazards) or libm fallback.
// NEVER raw inline-asm v_exp_f32 (R9 lesson: TRANS hazard invisible to compiler).
__device__ __forceinline__ float exp2r(float x) {
#if __has_builtin(__builtin_amdgcn_exp2f)
    return __builtin_amdgcn_exp2f(x);
#else
    return exp2f(x);
#endif
}

#define GL2L16(g, l) __builtin_amdgcn_global_load_lds( \
    (__attribute__((address_space(1))) void*)(void*)(g), \
    (__attribute__((address_space(3))) void*)(l), 16, 0, 0)

// 128B-row tiles (K and V both, at KT=64): slot = row&7  (R4-R17-verified)
__device__ __forceinline__ unsigned int kswz(unsigned int row, unsigned int cb) {
    return row * 128u + (cb ^ ((row & 7u) << 4));
}

// fused prep: blocks [0,2048) convert K fp32->bf16; blocks [2048,3072) transpose V
__global__ __launch_bounds__(256) void prep_kernel(const float* __restrict__ K,
                                                   unsigned short* __restrict__ Kb,
                                                   const float* __restrict__ V,
                                                   unsigned short* __restrict__ Vt) {
    __shared__ float tile[64][65];
    const int tid = threadIdx.x;
    if (blockIdx.x < 2048) {
        int i = blockIdx.x * 256 + tid;
        const float4* s = reinterpret_cast<const float4*>(K) + (size_t)i * 2;
        float4 a = s[0], b = s[1];
        short8_t o;
        o[0] = (short)f2bf(a.x); o[1] = (short)f2bf(a.y);
        o[2] = (short)f2bf(a.z); o[3] = (short)f2bf(a.w);
        o[4] = (short)f2bf(b.x); o[5] = (short)f2bf(b.y);
        o[6] = (short)f2bf(b.z); o[7] = (short)f2bf(b.w);
        *reinterpret_cast<short8_t*>(Kb + (size_t)i * 8) = o;
        return;
    }
    const int vbid = blockIdx.x - 2048;
    const int bh = vbid >> 5;
    const int t0 = (vbid & 31) * 64;
    const float* src = V + ((size_t)bh * TSEQ + t0) * DH;
#pragma unroll
    for (int it = 0; it < 4; ++it) {
        int idx = tid + it * 256;
        int row = idx >> 4;
        int c   = (idx & 15) * 4;
        float4 v = *reinterpret_cast<const float4*>(src + row * DH + c);
        tile[row][c + 0] = v.x; tile[row][c + 1] = v.y;
        tile[row][c + 2] = v.z; tile[row][c + 3] = v.w;
    }
    __syncthreads();
#pragma unroll
    for (int it = 0; it < 4; ++it) {
        int idx = tid + it * 256;
        int d  = idx >> 4;
        int c  = (idx & 15) * 4;
        ushort4_t o;
        o[0] = f2bf(tile[c + 0][d]); o[1] = f2bf(tile[c + 1][d]);
        o[2] = f2bf(tile[c + 2][d]); o[3] = f2bf(tile[c + 3][d]);
        *reinterpret_cast<ushort4_t*>(Vt + ((size_t)bh * DH + d) * TSEQ + t0 + c) = o;
    }
}

// Flash attention: R17 body, KT=64 rounds (2 sequential 32k-subtiles per barrier
// round -> 16 rounds instead of 32; per-round fixed overhead halved).
// 256 threads = 2 k-streams x 2 q-waves (64 q each via 2 q-sets).
// 2 bufs x 32KB {K s0|K s1|V s0|V s1 @ 8KB} + 8KB mask = 72KB -> 2 blocks/CU.
// Counted-vmcnt(8) 2-deep staging, R10-verified two-barrier skeleton.
__global__ __launch_bounds__(256, 2) void attn_kernel(const float* __restrict__ Qf,
                                                      const unsigned short* __restrict__ Kb,
                                                      const unsigned short* __restrict__ Vt,
                                                      const float* __restrict__ mask,
                                                      float* __restrict__ out) {
    // buf0 @0, buf1 @32K (each: K s0 0-8K | K s1 8-16K | V s0 16-24K | V s1 24-32K)
    // mask f32 @64K..72K
    __shared__ char lds[73728];
    float* smsk = reinterpret_cast<float*>(lds + 65536);

    const int tid  = threadIdx.x;
    const int wave = tid >> 6;
    const int lane = tid & 63;
    const int l31  = lane & 31;
    const int hi   = lane >> 5;
    const int s    = wave >> 1;    // k-stream
    const int qw   = wave & 1;     // q-wave (64 rows)

    // bijective XCD swizzle (512 blocks % 8 == 0): 4 bh per XCD
    const int bid = blockIdx.x;
    const int bh  = (bid & 7) * 4 + (bid >> 7);
    const int qb  = (bid >> 3) & 15;
    const int q0  = qb * 128 + qw * 64;
    const int b   = bh >> 4;

    // staging: 32 segs x 1KB per buffer. K: segs 0-15 (stream seg>>3, 8-row
    // quarter seg&7); V: segs 16-31 (same, d-rows). Wave w stages quarters
    // {w, w+4} of each of {K s0, K s1, V s0, V s1} = 8 segs.
    const char* gKc = reinterpret_cast<const char*>(Kb + (size_t)bh * TSEQ * DH);
    const char* gVc = reinterpret_cast<const char*>(Vt + (size_t)bh * DH * TSEQ);
    const unsigned int rA  = wave * 8 + (lane >> 3);        // rows 0..31
    const unsigned int rB  = rA + 32;                       // rows 32..63
    const unsigned int cb  = (lane & 7) * 16;
    const unsigned int scb = cb ^ (((lane >> 3) & 7u) << 4); // rA&7 == rB&7 == lane>>3
    const char* pk0a = gKc + (size_t)rA * 128 + scb;                 // K s0 rows 0-31
    const char* pk0b = gKc + (size_t)rB * 128 + scb;                 // K s0 rows 32-63
    const char* pk1a = pk0a + (size_t)1024 * 128;                    // K s1
    const char* pk1b = pk0b + (size_t)1024 * 128;
    const char* pv0a = gVc + (size_t)rA * 4096 + scb;                // V s0 d 0-31
    const char* pv0b = gVc + (size_t)rB * 4096 + scb;                // V s0 d 32-63
    const char* pv1a = pv0a + (size_t)1024 * 2;                      // V s1 (+2KB k-off)
    const char* pv1b = pv0b + (size_t)1024 * 2;
    const unsigned int lko0a = (wave +  0) * 1024 + lane * 16;   // K s0 quarter w
    const unsigned int lko0b = (wave +  4) * 1024 + lane * 16;   // K s0 quarter w+4
    const unsigned int lko1a = (wave +  8) * 1024 + lane * 16;   // K s1
    const unsigned int lko1b = (wave + 12) * 1024 + lane * 16;
    const unsigned int lvo0a = (wave + 16) * 1024 + lane * 16;   // V s0
    const unsigned int lvo0b = (wave + 20) * 1024 + lane * 16;
    const unsigned int lvo1a = (wave + 24) * 1024 + lane * 16;   // V s1
    const unsigned int lvo1b = (wave + 28) * 1024 + lane * 16;

    auto stage = [&](int buf) {
        char* base = lds + buf * 32768;
        GL2L16(pk0a, base + lko0a);
        GL2L16(pk0b, base + lko0b);
        GL2L16(pk1a, base + lko1a);
        GL2L16(pk1b, base + lko1b);
        GL2L16(pv0a, base + lvo0a);
        GL2L16(pv0b, base + lvo0b);
        GL2L16(pv1a, base + lvo1a);
        GL2L16(pv1b, base + lvo1b);
        pk0a += KT * 128; pk0b += KT * 128; pk1a += KT * 128; pk1b += KT * 128;
        pv0a += KT * 2;   pv0b += KT * 2;   pv1a += KT * 2;   pv1b += KT * 2;
    };

    // prologue: tiles 0 -> buf0, 1 -> buf1 (16 loads in flight)
    stage(0);
    stage(1);

    // stage mask row: *log2e - MSUB
    {
        const float4* m4 = reinterpret_cast<const float4*>(mask + (size_t)b * TSEQ);
        float4* s4 = reinterpret_cast<float4*>(smsk);
#pragma unroll
        for (int i = 0; i < 2; ++i) {
            int idx = tid + i * 256;
            float4 v = m4[idx];
            float4 w;
            w.x = v.x * LOG2E - MSUB; w.y = v.y * LOG2E - MSUB;
            w.z = v.z * LOG2E - MSUB; w.w = v.w * LOG2E - MSUB;
            s4[idx] = w;
        }
    }

    // Q B-frags (2 q-sets) from fp32 global, scale*log2e folded [R7-R17-verified]
    const float QS = 0.125f * LOG2E;
    short8_t qfA[4], qfB[4];
#pragma unroll
    for (int qs = 0; qs < 2; ++qs) {
        const float* qrow = Qf + ((size_t)bh * TSEQ + q0 + qs * 32 + l31) * DH;
#pragma unroll
        for (int dc = 0; dc < 4; ++dc) {
            float4 v0 = *reinterpret_cast<const float4*>(qrow + 16 * dc + 8 * hi);
            float4 v1 = *reinterpret_cast<const float4*>(qrow + 16 * dc + 8 * hi + 4);
            union { unsigned int u[4]; short8_t s8; } pk;
            pk.u[0] = cvtpk(v0.x * QS, v0.y * QS);
            pk.u[1] = cvtpk(v0.z * QS, v0.w * QS);
            pk.u[2] = cvtpk(v1.x * QS, v1.y * QS);
            pk.u[3] = cvtpk(v1.z * QS, v1.w * QS);
            if (qs == 0) qfA[dc] = pk.s8; else qfB[dc] = pk.s8;
        }
    }

    f32x16 oA0, oA1, oB0, oB1;
#pragma unroll
    for (int r = 0; r < 16; ++r) { oA0[r] = 0.f; oA1[r] = 0.f; oB0[r] = 0.f; oB1[r] = 0.f; }
    float lA = 0.f, lB = 0.f;

    const int kofs = s * 1024;

    // One 32k subtile (kb in {0,1}) of tile it from buffer bb: R17 body verbatim,
    // with K rows kb*32+.. and V k-bytes kb*64+.. inside the 128B-row tiles.
    auto subtile = [&](const char* bb, int it, int kb) {
        const char* cK = bb + s * 8192;
        const char* cV = bb + 16384 + s * 8192;

        // K A-frags (shared by both q-sets)
        short8_t kf0 = *reinterpret_cast<const short8_t*>(cK + kswz(kb * 32 + l31, 16 * hi));
        short8_t kf1 = *reinterpret_cast<const short8_t*>(cK + kswz(kb * 32 + l31, 32 + 16 * hi));
        short8_t kf2 = *reinterpret_cast<const short8_t*>(cK + kswz(kb * 32 + l31, 64 + 16 * hi));
        short8_t kf3 = *reinterpret_cast<const short8_t*>(cK + kswz(kb * 32 + l31, 96 + 16 * hi));

        // C-init with (mask*log2e - MSUB), reused by both q-sets
        const float* mb = &smsk[kofs + it * KT + kb * 32 + 4 * hi];
        float4 mv0 = *reinterpret_cast<const float4*>(mb);
        float4 mv1 = *reinterpret_cast<const float4*>(mb + 8);
        float4 mv2 = *reinterpret_cast<const float4*>(mb + 16);
        float4 mv3 = *reinterpret_cast<const float4*>(mb + 24);
        f32x16 scA;
        scA[0]  = mv0.x; scA[1]  = mv0.y; scA[2]  = mv0.z; scA[3]  = mv0.w;
        scA[4]  = mv1.x; scA[5]  = mv1.y; scA[6]  = mv1.z; scA[7]  = mv1.w;
        scA[8]  = mv2.x; scA[9]  = mv2.y; scA[10] = mv2.z; scA[11] = mv2.w;
        scA[12] = mv3.x; scA[13] = mv3.y; scA[14] = mv3.z; scA[15] = mv3.w;
        f32x16 scB = scA;

        // S^T = K . Q^T for both q-sets (K frags reused)
        __builtin_amdgcn_s_setprio(1);
        scA = __builtin_amdgcn_mfma_f32_32x32x16_bf16(kf0, qfA[0], scA, 0, 0, 0);
        scB = __builtin_amdgcn_mfma_f32_32x32x16_bf16(kf0, qfB[0], scB, 0, 0, 0);
        scA = __builtin_amdgcn_mfma_f32_32x32x16_bf16(kf1, qfA[1], scA, 0, 0, 0);
        scB = __builtin_amdgcn_mfma_f32_32x32x16_bf16(kf1, qfB[1], scB, 0, 0, 0);
        scA = __builtin_amdgcn_mfma_f32_32x32x16_bf16(kf2, qfA[2], scA, 0, 0, 0);
        scB = __builtin_amdgcn_mfma_f32_32x32x16_bf16(kf2, qfB[2], scB, 0, 0, 0);
        scA = __builtin_amdgcn_mfma_f32_32x32x16_bf16(kf3, qfA[3], scA, 0, 0, 0);
        scB = __builtin_amdgcn_mfma_f32_32x32x16_bf16(kf3, qfB[3], scB, 0, 0, 0);
        __builtin_amdgcn_s_setprio(0);

        // V A-frags (shared by both q-sets); k-bytes = kb*64 + 32c + 16hi
        short8_t vf00 = *reinterpret_cast<const short8_t*>(cV + kswz(l31,      kb * 64 + 16 * hi));
        short8_t vf01 = *reinterpret_cast<const short8_t*>(cV + kswz(32 + l31, kb * 64 + 16 * hi));
        short8_t vf10 = *reinterpret_cast<const short8_t*>(cV + kswz(l31,      kb * 64 + 32 + 16 * hi));
        short8_t vf11 = *reinterpret_cast<const short8_t*>(cV + kswz(32 + l31, kb * 64 + 32 + 16 * hi));

        // fused softmax (raw exp2 + l-add + cvtpk), 2 halves interleaved with PV
#pragma unroll
        for (int c = 0; c < 2; ++c) {
            unsigned int a0, a1, a2, a3, b0, b1, b2, b3;
            {
                float e0 = exp2r(scA[8*c+0]), e1 = exp2r(scA[8*c+1]);
                float e2 = exp2r(scA[8*c+2]), e3 = exp2r(scA[8*c+3]);
                float e4 = exp2r(scA[8*c+4]), e5 = exp2r(scA[8*c+5]);
                float e6 = exp2r(scA[8*c+6]), e7 = exp2r(scA[8*c+7]);
                lA += ((e0+e1)+(e2+e3)) + ((e4+e5)+(e6+e7));
                a0 = cvtpk(e0, e1); a2 = cvtpk(e2, e3);
                a1 = cvtpk(e4, e5); a3 = cvtpk(e6, e7);
            }
            {
                float e0 = exp2r(scB[8*c+0]), e1 = exp2r(scB[8*c+1]);
                float e2 = exp2r(scB[8*c+2]), e3 = exp2r(scB[8*c+3]);
                float e4 = exp2r(scB[8*c+4]), e5 = exp2r(scB[8*c+5]);
                float e6 = exp2r(scB[8*c+6]), e7 = exp2r(scB[8*c+7]);
                lB += ((e0+e1)+(e2+e3)) + ((e4+e5)+(e6+e7));
                b0 = cvtpk(e0, e1); b2 = cvtpk(e2, e3);
                b1 = cvtpk(e4, e5); b3 = cvtpk(e6, e7);
            }
            asm("v_permlane32_swap_b32 %0, %1" : "+v"(a0), "+v"(a1));
            asm("v_permlane32_swap_b32 %0, %1" : "+v"(a2), "+v"(a3));
            asm("v_permlane32_swap_b32 %0, %1" : "+v"(b0), "+v"(b1));
            asm("v_permlane32_swap_b32 %0, %1" : "+v"(b2), "+v"(b3));
            union { unsigned int u[4]; short8_t s8; } pfA, pfB;
            pfA.u[0] = a0; pfA.u[1] = a2; pfA.u[2] = a1; pfA.u[3] = a3;
            pfB.u[0] = b0; pfB.u[1] = b2; pfB.u[2] = b1; pfB.u[3] = b3;
            short8_t vf0 = c ? vf10 : vf00;
            short8_t vf1 = c ? vf11 : vf01;
            __builtin_amdgcn_s_setprio(1);
            oA0 = __builtin_amdgcn_mfma_f32_32x32x16_bf16(vf0, pfA.s8, oA0, 0, 0, 0);
            oB0 = __builtin_amdgcn_mfma_f32_32x32x16_bf16(vf0, pfB.s8, oB0, 0, 0, 0);
            oA1 = __builtin_amdgcn_mfma_f32_32x32x16_bf16(vf1, pfA.s8, oA1, 0, 0, 0);
            oB1 = __builtin_amdgcn_mfma_f32_32x32x16_bf16(vf1, pfB.s8, oB1, 0, 0, 0);
            __builtin_amdgcn_s_setprio(0);
        }
    };

    __syncthreads();   // mask + tiles 0,1 visible (full drain, one-time)

    // main loop: two-barrier rounds (R10 skeleton), 2 subtiles per round
    for (int t = 0; t < NIT - 1; ++t) {
        asm volatile("s_waitcnt vmcnt(8)" ::: "memory");   // my tile-t 8 loads landed
        __builtin_amdgcn_s_barrier();                      // all waves' tile-t loads landed
        __builtin_amdgcn_sched_barrier(0);
        const char* bb = lds + (t & 1) * 32768;
        subtile(bb, t, 0);
        subtile(bb, t, 1);
        __builtin_amdgcn_sched_barrier(0);
        __builtin_amdgcn_s_barrier();                      // all waves done with buf t&1
        __builtin_amdgcn_sched_barrier(0);
        if (t < NIT - 2) stage(t & 1);                     // tile t+2 -> freed buffer
    }
    asm volatile("s_waitcnt vmcnt(0)" ::: "memory");
    __builtin_amdgcn_s_barrier();
    __builtin_amdgcn_sched_barrier(0);
    {
        const char* bb = lds + ((NIT - 1) & 1) * 32768;
        subtile(bb, NIT - 1, 0);
        subtile(bb, NIT - 1, 1);
    }

    __syncthreads();   // LDS reusable for merge

    // split-K merge: static max -> partials just add. Stream-1 waves write O^T,l.
    float lAt = lA + __shfl_xor(lA, 32);
    float lBt = lB + __shfl_xor(lB, 32);
    if (s == 1) {
#pragma unroll
        for (int qs = 0; qs < 2; ++qs) {
            char* wp = lds + qw * 16384 + qs * 8192;
            const f32x16& o0 = qs ? oB0 : oA0;
            const f32x16& o1 = qs ? oB1 : oA1;
#pragma unroll
            for (int i = 0; i < 8; ++i) {
                float4 v;
                if (i < 4) { v.x = o0[4*i]; v.y = o0[4*i+1]; v.z = o0[4*i+2]; v.w = o0[4*i+3]; }
                else       { v.x = o1[4*(i-4)]; v.y = o1[4*(i-4)+1]; v.z = o1[4*(i-4)+2]; v.w = o1[4*(i-4)+3]; }
                *reinterpret_cast<float4*>(wp + lane * 128 + ((i * 16) ^ ((lane & 7u) << 4))) = v;
            }
        }
        if (hi == 0) {
            reinterpret_cast<float*>(lds + 65536 + (qw * 2 + 0) * 128)[l31] = lAt;
            reinterpret_cast<float*>(lds + 65536 + (qw * 2 + 1) * 128)[l31] = lBt;
        }
    }
    __syncthreads();
    if (s == 0) {
#pragma unroll
        for (int qs = 0; qs < 2; ++qs) {
            const char* rp = lds + qw * 16384 + qs * 8192;
            const f32x16& o0 = qs ? oB0 : oA0;
            const f32x16& o1 = qs ? oB1 : oA1;
            float lpart = qs ? lBt : lAt;
            float ltt = lpart + reinterpret_cast<const float*>(lds + 65536 + (qw * 2 + qs) * 128)[l31];
            float inv = 1.0f / ltt;
            float* orow = out + ((size_t)bh * TSEQ + q0 + qs * 32 + l31) * DH;
#pragma unroll
            for (int i = 0; i < 8; ++i) {
                float4 o = *reinterpret_cast<const float4*>(rp + lane * 128 + ((i * 16) ^ ((lane & 7u) << 4)));
                float4 v;
                if (i < 4) {
                    v.x = (o0[4*i]   + o.x) * inv; v.y = (o0[4*i+1] + o.y) * inv;
                    v.z = (o0[4*i+2] + o.z) * inv; v.w = (o0[4*i+3] + o.w) * inv;
                } else {
                    v.x = (o1[4*(i-4)]   + o.x) * inv; v.y = (o1[4*(i-4)+1] + o.y) * inv;
                    v.z = (o1[4*(i-4)+2] + o.z) * inv; v.w = (o1[4*(i-4)+3] + o.w) * inv;
                }
                const int db = i >> 2, rr = i & 3;
                *reinterpret_cast<float4*>(orow + 32 * db + 8 * rr + 4 * hi) = v;
            }
        }
    }
}

extern "C" void kernel_launch(void* const* d_in, const int* in_sizes, int n_in,
                              void* d_out, int out_size, void* d_ws, size_t ws_size,
                              hipStream_t stream) {
    const float* Q    = (const float*)d_in[0];
    const float* K    = (const float*)d_in[1];
    const float* V    = (const float*)d_in[2];
    const float* mask = (const float*)d_in[3];
    float* out = (float*)d_out;

    const size_t N = (size_t)NBH * TSEQ * DH;
    unsigned short* Kb = (unsigned short*)d_ws;   // 8 MB
    unsigned short* Vt = Kb + N;                  // 8 MB

    hipLaunchKernelGGL(prep_kernel, dim3(2048 + 1024), dim3(256), 0, stream, K, Kb, V, Vt);
    hipLaunchKernelGGL(attn_kernel, dim3(16 * NBH), dim3(256), 0, stream,
                       Q, Kb, Vt, mask, out);
}